// Round 1
// baseline (11471.885 us; speedup 1.0000x reference)
//
#include <hip/hip_runtime.h>
#include <hip/hip_bf16.h>
#include <math.h>

// ---------------------------------------------------------------------------
// BabiUTransformer (Universal Transformer + ACT) on gfx950.  All float I/O fp32.
// GEMMs: split-precision bf16 MFMA (hh+lh+hl, err ~2^-18 rel). Activations are
// pre-split into hi/lo bf16 planes by their PRODUCER kernels.
// GEMM v2 (this round): 128x128 tile, BK=32, 4 waves (64x64 quadrant each,
// 4x4 fragments), global_load_lds width-16 staging (m97 ladder structure).
// LDS layout is [group16][kchunk8][row16] subtiles so fragment ds_read_b128s
// are 1KiB-contiguous per wave (conflict-free); the lane permutation is
// carried on the per-lane GLOBAL source address (legal with global_load_lds).
// Conv edge zero-fill via per-lane redirect of the source pointer to a
// zeroed 256B page (numerically identical to the old register zero-fill).
// Attention: LDS stride padded 64->65 (kills 64-way bank conflict).
// ACT any()-gate via per-step device flag (ballot-reduced).
// ---------------------------------------------------------------------------

typedef unsigned short ushort_t;
using short8  = __attribute__((ext_vector_type(8))) short;
using floatx4 = __attribute__((ext_vector_type(4))) float;

#define B_   256
#define L_   71
#define H_   512
#define M_   (B_*L_)      // 18176 rows (142 x 128); half = 9088 (71 x 128)
#define MH_  9088
#define FS_  2048
#define V_   32000
#define NH_  8
#define DK_  64

__device__ inline ushort_t f2bf_rne(float f) {
    unsigned u = __float_as_uint(f);
    return (ushort_t)((u + 0x7FFFu + ((u >> 16) & 1u)) >> 16);
}

// async global->LDS, 16B per lane. LDS dest must be wave-uniform base
// (hardware writes base + lane*16); global src is per-lane.
__device__ __forceinline__ void gload16(const void* g, void* l)
{
    __builtin_amdgcn_global_load_lds(
        (__attribute__((address_space(1))) unsigned int*)(g),
        (__attribute__((address_space(3))) unsigned int*)(l),
        16, 0, 0);
}

// ---------------------------------------------------------------------------
// Split GEMM: C[M,N] = alpha*(A @ B) (+bias)(+residual)(relu)
// A pre-split hi/lo bf16 planes [rows, lda]. B hi/lo planes [N,K] row-major.
// conv=1: row m's 3C window starts at A row (am+rowA-1); k-chunk d==0 invalid
//   at l==0, d==2 invalid at l==70 (zero via zpg redirect). l from (am+rowG)%71.
// outMode: 0 = f32 out; 1 = f32 out + fused prev-update; 2 = bf16 hi/lo out.
// Tile 128x128, BK=32. Grid: (N/128, M/128). 256 threads.
// ---------------------------------------------------------------------------
__global__ __launch_bounds__(256) void gemm_s(
    const ushort_t* __restrict__ AH, const ushort_t* __restrict__ AL,
    int lda, int conv, int rowA, int rowG,
    const ushort_t* __restrict__ Bh, const ushort_t* __restrict__ Bl,
    int N, int K,
    const float* __restrict__ bias, const float* residual,
    float alpha, int relu, int rowC, int outMode,
    float* Cout, ushort_t* CoutH, ushort_t* CoutL,
    float* prev, const float* __restrict__ uw,
    const ushort_t* __restrict__ zpg)
{
    // per plane: 8 groups x [4 kchunks x 16 rows] x 8 shorts = 4096 shorts (8KB)
    __shared__ __attribute__((aligned(16))) short Ahs[4096], Als[4096];
    __shared__ __attribute__((aligned(16))) short Bhs[4096], Bls[4096];

    const int tid  = threadIdx.x;
    const int w    = tid >> 6, lane = tid & 63;
    const int bm = blockIdx.y << 7, bn = blockIdx.x << 7;

    // ---- staging setup: wave w stages groups {w, w+4} of each plane ----
    const int srow = lane & 15;        // row within 16-row group
    const int skc  = lane >> 4;        // k-chunk (8 shorts) 0..3
    const int ra0  = w * 16 + srow;    // tile rows this thread stages
    const int ra1  = ra0 + 64;
    const int am0  = bm + ra0, am1 = bm + ra1;
    const int ash  = conv ? (rowA - 1) : rowA;
    const ushort_t* pAh0 = AH + (long)(am0 + ash) * lda + skc * 8;
    const ushort_t* pAl0 = AL + (long)(am0 + ash) * lda + skc * 8;
    const ushort_t* pAh1 = AH + (long)(am1 + ash) * lda + skc * 8;
    const ushort_t* pAl1 = AL + (long)(am1 + ash) * lda + skc * 8;
    int l0 = 0, l1 = 0;
    if (conv) { l0 = (am0 + rowG) % 71; l1 = (am1 + rowG) % 71; }
    const ushort_t* pBh0 = Bh + (long)(bn + ra0) * K + skc * 8;
    const ushort_t* pBl0 = Bl + (long)(bn + ra0) * K + skc * 8;
    const ushort_t* pBh1 = Bh + (long)(bn + ra1) * K + skc * 8;
    const ushort_t* pBl1 = Bl + (long)(bn + ra1) * K + skc * 8;

    // ---- fragment read offsets: wave reads 1KiB contiguous (conflict-free) ----
    const int quad = lane >> 4, mr = lane & 15;
    const int wr = (w >> 1) << 6, wc = (w & 1) << 6;   // wave quadrant origin
    const int aoff = (wr >> 4) * 512 + quad * 128 + mr * 8;  // + i*512 (shorts)
    const int boff = (wc >> 4) * 512 + quad * 128 + mr * 8;  // + j*512

    floatx4 acc[4][4] = {};

    for (int k0 = 0; k0 < K; k0 += 32) {
        const ushort_t* sA0h = pAh0 + k0;
        const ushort_t* sA0l = pAl0 + k0;
        const ushort_t* sA1h = pAh1 + k0;
        const ushort_t* sA1l = pAl1 + k0;
        if (conv) {
            // lda is a multiple of 32 -> d uniform across the K-step
            const int d = (k0 >= lda) ? ((k0 >= 2 * lda) ? 2 : 1) : 0;
            if ((l0 == 0 && d == 0) || (l0 == 70 && d == 2)) { sA0h = zpg; sA0l = zpg; }
            if ((l1 == 0 && d == 0) || (l1 == 70 && d == 2)) { sA1h = zpg; sA1l = zpg; }
        }
        __syncthreads();   // previous step's ds_reads done before overwrite
        gload16(sA0h,      Ahs + w * 512);
        gload16(sA1h,      Ahs + (w + 4) * 512);
        gload16(sA0l,      Als + w * 512);
        gload16(sA1l,      Als + (w + 4) * 512);
        gload16(pBh0 + k0, Bhs + w * 512);
        gload16(pBh1 + k0, Bhs + (w + 4) * 512);
        gload16(pBl0 + k0, Bls + w * 512);
        gload16(pBl1 + k0, Bls + (w + 4) * 512);
        __syncthreads();   // compiler drains vmcnt(0) here (loads landed)

        short8 ah[4], al[4], bh[4], bl[4];
        #pragma unroll
        for (int i = 0; i < 4; i++) {
            ah[i] = *(const short8*)(Ahs + aoff + i * 512);
            al[i] = *(const short8*)(Als + aoff + i * 512);
            bh[i] = *(const short8*)(Bhs + boff + i * 512);
            bl[i] = *(const short8*)(Bls + boff + i * 512);
        }
        #pragma unroll
        for (int i = 0; i < 4; i++)
        #pragma unroll
        for (int j = 0; j < 4; j++) {
            acc[i][j] = __builtin_amdgcn_mfma_f32_16x16x32_bf16(ah[i], bh[j], acc[i][j], 0, 0, 0);
            acc[i][j] = __builtin_amdgcn_mfma_f32_16x16x32_bf16(al[i], bh[j], acc[i][j], 0, 0, 0);
            acc[i][j] = __builtin_amdgcn_mfma_f32_16x16x32_bf16(ah[i], bl[j], acc[i][j], 0, 0, 0);
        }
    }

    // C/D layout: col = lane&15, row = quad*4 + r  [verified m89/m91]
    #pragma unroll
    for (int j = 0; j < 4; j++) {
        const int gcol = bn + wc + j * 16 + mr;
        const float bv = bias ? bias[gcol] : 0.f;
        #pragma unroll
        for (int i = 0; i < 4; i++) {
            #pragma unroll
            for (int r = 0; r < 4; r++) {
                const int grow = bm + wr + i * 16 + quad * 4 + r;
                const long crow = (long)grow + rowC;
                float v = acc[i][j][r] * alpha + bv;
                if (residual) v += residual[crow * N + gcol];
                if (relu) v = fmaxf(v, 0.f);
                const long cidx = crow * (long)N + gcol;
                if (outMode == 2) {
                    ushort_t h = f2bf_rne(v);
                    float hf = __uint_as_float(((unsigned)h) << 16);
                    CoutH[cidx] = h;
                    CoutL[cidx] = f2bf_rne(v - hf);
                } else {
                    Cout[cidx] = v;
                    if (outMode == 1) {
                        float u = uw[crow];
                        prev[cidx] = v * u + prev[cidx] * (1.f - u);
                    }
                }
            }
        }
    }
}

// Timing-signal tables, float32 math (matches numpy float32 exp/sin chain).
__global__ __launch_bounds__(256) void sig_prep(float* __restrict__ T, float* __restrict__ P)
{
    int i = blockIdx.x * 256 + threadIdx.x;
    const int NT = 71 * 512;
    if (i >= NT + 6 * 512) return;
    int pos, c, idx;
    float* dst;
    if (i < NT) { pos = i >> 9; c = i & 511; dst = T; idx = i; }
    else        { int j = i - NT; pos = j >> 9; c = j & 511; dst = P; idx = j; }
    const float loginc = 0.036119766f;
    int jj = c & 255;
    float inv = expf(-(float)jj * loginc);
    float arg = (float)pos * inv;
    dst[idx] = (c < 256) ? sinf(arg) : cosf(arg);
}

// active-gate: flag |= any(hp<0.9 && nu<6)   (ballot, 1 atomic/wave)
__global__ __launch_bounds__(256) void gate_kernel(
    const float* __restrict__ hp, const float* __restrict__ nu, int* __restrict__ flag)
{
    int i = blockIdx.x * 256 + threadIdx.x;
    bool act = (i < M_) && (hp[i] < 0.9f) && (nu[i] < 6.0f);
    unsigned long long b = __ballot(act);
    if ((threadIdx.x & 63) == 0 && b) atomicOr(flag, 1);
}

// s = state + T[l] + P[t] (in-place); pr = sigmoid(s.p_w+p_b); gated ACT.
__global__ __launch_bounds__(256) void s_pr_kernel(
    float* trunk, const float* __restrict__ Ttab, const float* __restrict__ Ptab,
    const float* __restrict__ p_w, const float* __restrict__ p_b,
    float* __restrict__ hp, float* __restrict__ rem, float* __restrict__ nu,
    float* __restrict__ uw, const int* __restrict__ flag, int t)
{
    const int row  = blockIdx.x * 4 + (threadIdx.x >> 6);
    const int lane = threadIdx.x & 63;
    const int l    = row % 71;
    float dot = 0.f;
    #pragma unroll
    for (int j = 0; j < 8; j++) {
        int c  = lane + 64 * j;
        float sv = trunk[(long)row * H_ + c] + Ttab[l * H_ + c] + Ptab[t * H_ + c];
        trunk[(long)row * H_ + c] = sv;
        dot += sv * p_w[c];
    }
    #pragma unroll
    for (int o = 32; o; o >>= 1) dot += __shfl_xor(dot, o);
    if (lane == 0) {
        if (flag[0]) {
            float pr = 1.f / (1.f + expf(-(dot + p_b[0])));
            float hp0 = hp[row], rem0 = rem[row], nu0 = nu[row];
            float still = (hp0 < 1.0f) ? 1.f : 0.f;
            float tot   = hp0 + pr * still;
            float nh    = ((tot > 0.9f) ? 1.f : 0.f) * still;
            float st2   = ((tot <= 0.9f) ? 1.f : 0.f) * still;
            float hp2   = hp0 + pr * st2;
            float rem2  = rem0 + nh * (1.f - hp2);
            hp2 += nh * rem2;
            hp[row] = hp2; rem[row] = rem2; nu[row] = nu0 + st2 + nh;
            uw[row] = pr * st2 + nh * rem2;
        } else {
            uw[row] = 0.f;
        }
    }
}

// LayerNorm fp32 -> bf16 hi/lo planes.
__global__ __launch_bounds__(256) void ln_kernel(
    const float* __restrict__ X, const float* __restrict__ g,
    const float* __restrict__ bb, ushort_t* __restrict__ outH,
    ushort_t* __restrict__ outL)
{
    const int row  = blockIdx.x * 4 + (threadIdx.x >> 6);
    const int lane = threadIdx.x & 63;
    const float* xr = X + (long)row * H_;
    float v[8];
    float s = 0.f;
    #pragma unroll
    for (int j = 0; j < 8; j++) { v[j] = xr[lane + 64 * j]; s += v[j]; }
    #pragma unroll
    for (int o = 32; o; o >>= 1) s += __shfl_xor(s, o);
    float mean = s * (1.f / 512.f);
    float q = 0.f;
    #pragma unroll
    for (int j = 0; j < 8; j++) { float d = v[j] - mean; q += d * d; }
    #pragma unroll
    for (int o = 32; o; o >>= 1) q += __shfl_xor(q, o);
    float sd  = sqrtf(q * (1.f / 511.f));
    float inv = 1.f / (sd + 1e-6f);
    #pragma unroll
    for (int j = 0; j < 8; j++) {
        int c = lane + 64 * j;
        float val = g[c] * (v[j] - mean) * inv + bb[c];
        ushort_t h = f2bf_rne(val);
        float hf = __uint_as_float(((unsigned)h) << 16);
        long idx = (long)row * H_ + c;
        outH[idx] = h;
        outL[idx] = f2bf_rne(val - hf);
    }
}

// Attention, fp32, LDS stride 65 (conflict-free). One block per (b,h).
// q pre-scaled by 1/8 in the q-GEMM. ctx written as bf16 hi/lo planes.
__global__ __launch_bounds__(256) void attn_kernel(
    const float* __restrict__ q, const float* __restrict__ k,
    const float* __restrict__ v, ushort_t* __restrict__ ctxH,
    ushort_t* __restrict__ ctxL)
{
    __shared__ float qs[L_ * 65];
    __shared__ float ks[L_ * 65];   // reused for V
    __shared__ float Ss[L_ * L_];
    const int tid = threadIdx.x;
    const int b = blockIdx.x >> 3, h = blockIdx.x & 7;
    const long base = (long)b * L_ * H_ + h * DK_;
    for (int idx = tid; idx < L_ * DK_; idx += 256) {
        int i = idx >> 6, d = idx & 63;
        qs[i * 65 + d] = q[base + (long)i * H_ + d];
        ks[i * 65 + d] = k[base + (long)i * H_ + d];
    }
    __syncthreads();
    for (int idx = tid; idx < L_ * L_; idx += 256) {
        int i = idx / 71, j = idx % 71;
        const float* qr = qs + i * 65;
        const float* kr = ks + j * 65;
        float s0 = 0.f, s1 = 0.f, s2 = 0.f, s3 = 0.f;
        #pragma unroll
        for (int d = 0; d < 64; d += 4) {
            s0 += qr[d]     * kr[d];
            s1 += qr[d + 1] * kr[d + 1];
            s2 += qr[d + 2] * kr[d + 2];
            s3 += qr[d + 3] * kr[d + 3];
        }
        Ss[i * 71 + j] = (s0 + s1) + (s2 + s3);
    }
    __syncthreads();
    if (tid < L_) {
        float mx = -1e30f;
        for (int j = 0; j < L_; j++) mx = fmaxf(mx, Ss[tid * 71 + j]);
        float sm = 0.f;
        for (int j = 0; j < L_; j++) { float e = expf(Ss[tid * 71 + j] - mx); Ss[tid * 71 + j] = e; sm += e; }
        float inv = 1.f / sm;
        for (int j = 0; j < L_; j++) Ss[tid * 71 + j] *= inv;
    }
    for (int idx = tid; idx < L_ * DK_; idx += 256) {
        int i = idx >> 6, d = idx & 63;
        ks[i * 65 + d] = v[base + (long)i * H_ + d];
    }
    __syncthreads();
    for (int idx = tid; idx < L_ * DK_; idx += 256) {
        int i = idx >> 6, d = idx & 63;
        const float* sr = Ss + i * 71;
        float s0 = 0.f, s1 = 0.f;
        int j = 0;
        for (; j + 1 < L_; j += 2) {
            s0 += sr[j]     * ks[j * 65 + d];
            s1 += sr[j + 1] * ks[(j + 1) * 65 + d];
        }
        float s = s0 + s1 + sr[70] * ks[70 * 65 + d];
        ushort_t hh = f2bf_rne(s);
        float hf = __uint_as_float(((unsigned)hh) << 16);
        long o = base + (long)i * H_ + d;
        ctxH[o] = hh;
        ctxL[o] = f2bf_rne(s - hf);
    }
}

// Embedding -> bf16 hi/lo planes
__global__ __launch_bounds__(256) void embed_kernel(
    const int* __restrict__ story, const int* __restrict__ query,
    const float* __restrict__ emb, const float* __restrict__ mask,
    ushort_t* __restrict__ xH, ushort_t* __restrict__ xL)
{
    __shared__ int idx[11];
    const int row = blockIdx.x;
    const int b = row / 71, m = row % 71;
    const int tid = threadIdx.x;
    if (tid < 11)
        idx[tid] = (m < 70) ? story[((long)b * 70 + m) * 11 + tid]
                            : query[(long)b * 11 + tid];
    __syncthreads();
    for (int c = tid; c < H_; c += 256) {
        float acc = 0.f;
        #pragma unroll
        for (int s = 0; s < 11; s++)
            acc += emb[(long)idx[s] * H_ + c] * mask[s * H_ + c];
        ushort_t h = f2bf_rne(acc);
        float hf = __uint_as_float(((unsigned)h) << 16);
        long o = (long)row * H_ + c;
        xH[o] = h;
        xL[o] = f2bf_rne(acc - hf);
    }
}

// transpose + split fp32 [R,C] -> bf16 hi/lo planes [C,R]
__global__ __launch_bounds__(256) void wsplitT_kernel(
    const float* __restrict__ in, ushort_t* __restrict__ hi, ushort_t* __restrict__ lo,
    int R, int C)
{
    long i = (long)blockIdx.x * 256 + threadIdx.x;
    if (i < (long)R * C) {
        int r = (int)(i / C), c = (int)(i % C);
        float f = in[i];
        ushort_t h = f2bf_rne(f);
        float hf = __uint_as_float(((unsigned)h) << 16);
        hi[(long)c * R + r] = h;
        lo[(long)c * R + r] = f2bf_rne(f - hf);
    }
}

// conv weight gather+split: plane[n*(3C) + d*C + c] = w[(n*C + c)*3 + d]
__global__ __launch_bounds__(256) void convw_split_kernel(
    const float* __restrict__ w, ushort_t* __restrict__ hi, ushort_t* __restrict__ lo,
    int N, int C)
{
    long i = (long)blockIdx.x * 256 + threadIdx.x;
    if (i < (long)N * C * 3) {
        int n = (int)(i / (3 * C));
        int r = (int)(i % (3 * C));
        int d = r / C, c = r % C;
        float f = w[((long)n * C + c) * 3 + d];
        ushort_t h = f2bf_rne(f);
        float hf = __uint_as_float(((unsigned)h) << 16);
        hi[i] = h;
        lo[i] = f2bf_rne(f - hf);
    }
}

// plain split: emb [V,E] -> hi/lo planes same layout
__global__ __launch_bounds__(256) void esplit_kernel(
    const float* __restrict__ in, ushort_t* __restrict__ hi, ushort_t* __restrict__ lo,
    long n)
{
    long i = (long)blockIdx.x * 256 + threadIdx.x;
    if (i < n) {
        float f = in[i];
        ushort_t h = f2bf_rne(f);
        float hf = __uint_as_float(((unsigned)h) << 16);
        hi[i] = h;
        lo[i] = f2bf_rne(f - hf);
    }
}

__global__ __launch_bounds__(256) void zero_f32(float* __restrict__ p, long n)
{
    long i = (long)blockIdx.x * 256 + threadIdx.x;
    if (i < n) p[i] = 0.f;
}

// pooled[b,c] = (sum_l prev[b,l,c]) / 71 -> bf16 hi/lo planes
__global__ __launch_bounds__(256) void pooled_kernel(
    const float* __restrict__ prev, ushort_t* __restrict__ pH, ushort_t* __restrict__ pL)
{
    int i = blockIdx.x * 256 + threadIdx.x;   // [0, 256*512)
    int b = i >> 9, c = i & 511;
    float s = 0.f;
    for (int l = 0; l < L_; l++) s += prev[((long)b * L_ + l) * H_ + c];
    float p = s / 71.0f;
    ushort_t h = f2bf_rne(p);
    float hf = __uint_as_float(((unsigned)h) << 16);
    pH[i] = h;
    pL[i] = f2bf_rne(p - hf);
}

__global__ __launch_bounds__(256) void softmax_kernel(
    const float* __restrict__ ah, float* __restrict__ out)
{
    __shared__ float red[256];
    const int b = blockIdx.x, tid = threadIdx.x;
    const float* a = ah + (long)b * V_;
    float mx = -1e30f;
    for (int i = tid; i < V_; i += 256) mx = fmaxf(mx, a[i]);
    red[tid] = mx; __syncthreads();
    for (int o = 128; o; o >>= 1) { if (tid < o) red[tid] = fmaxf(red[tid], red[tid + o]); __syncthreads(); }
    mx = red[0]; __syncthreads();
    float s = 0.f;
    for (int i = tid; i < V_; i += 256) s += expf(a[i] - mx);
    red[tid] = s; __syncthreads();
    for (int o = 128; o; o >>= 1) { if (tid < o) red[tid] += red[tid + o]; __syncthreads(); }
    float inv = 1.f / red[0];
    float* o_ = out + (long)b * V_;
    for (int i = tid; i < V_; i += 256) o_[i] = expf(a[i] - mx) * inv;
}

__global__ __launch_bounds__(256) void tails_kernel(
    const float* __restrict__ rem, const float* __restrict__ nu, float* __restrict__ out)
{
    int i = blockIdx.x * 256 + threadIdx.x;
    if (i < M_) {
        out[i] = rem[i];
        out[M_ + i] = nu[i];
    }
}

// ---------------------------------------------------------------------------
extern "C" void kernel_launch(void* const* d_in, const int* in_sizes, int n_in,
                              void* d_out, int out_size, void* d_ws, size_t ws_size,
                              hipStream_t stream)
{
    const int*   story  = (const int*)d_in[0];
    const int*   query  = (const int*)d_in[1];
    const float* emb    = (const float*)d_in[2];
    const float* mask_p = (const float*)d_in[3];
    const float* proj_w = (const float*)d_in[4];
    const float* ln1_g  = (const float*)d_in[5];
    const float* ln1_b  = (const float*)d_in[6];
    const float* wq     = (const float*)d_in[7];
    const float* wk     = (const float*)d_in[8];
    const float* wv     = (const float*)d_in[9];
    const float* wo     = (const float*)d_in[10];
    const float* c1_w   = (const float*)d_in[11];
    const float* c1_b   = (const float*)d_in[12];
    const float* c2_w   = (const float*)d_in[13];
    const float* c2_b   = (const float*)d_in[14];
    const float* ln2_g  = (const float*)d_in[15];
    const float* ln2_b  = (const float*)d_in[16];
    const float* p_w    = (const float*)d_in[17];
    const float* p_b    = (const float*)d_in[18];
    const float* out_b  = (const float*)d_in[19];
    float* outp = (float*)d_out;

    char* wsb = (char*)d_ws;
    size_t off = 0;
    auto alloc = [&](size_t bytes) -> void* {
        void* p = wsb + off;
        off = (off + bytes + 255) & ~(size_t)255;
        return p;
    };
    const long ROWE = (long)M_ * H_;             // 9,306,112 elements

    float* trunkF = (float*)alloc(ROWE * 4);
    float* prevF  = (float*)alloc(ROWE * 4);
    char*  poolC  = (char*)alloc(4L * ROWE * 4); // 148.9 MB multi-purpose pool
    float* hpF    = (float*)alloc((long)M_ * 4 * 4 + 64);
    float* remF   = hpF + M_;
    float* nuF    = hpF + 2 * M_;
    float* uwF    = hpF + 3 * M_;
    int*   flags  = (int*)(hpF + 4 * M_);
    ushort_t* zpg   = (ushort_t*)alloc(256);     // zero page for conv edge chunks
    ushort_t* projH = (ushort_t*)alloc((long)H_ * H_ * 2);
    ushort_t* projL = (ushort_t*)alloc((long)H_ * H_ * 2);
    ushort_t* wqH   = (ushort_t*)alloc((long)H_ * H_ * 2);
    ushort_t* wqL   = (ushort_t*)alloc((long)H_ * H_ * 2);
    ushort_t* wkH   = (ushort_t*)alloc((long)H_ * H_ * 2);
    ushort_t* wkL   = (ushort_t*)alloc((long)H_ * H_ * 2);
    ushort_t* wvH   = (ushort_t*)alloc((long)H_ * H_ * 2);
    ushort_t* wvL   = (ushort_t*)alloc((long)H_ * H_ * 2);
    ushort_t* woH   = (ushort_t*)alloc((long)H_ * H_ * 2);
    ushort_t* woL   = (ushort_t*)alloc((long)H_ * H_ * 2);
    ushort_t* W1H   = (ushort_t*)alloc((long)FS_ * 3 * H_ * 2);
    ushort_t* W1L   = (ushort_t*)alloc((long)FS_ * 3 * H_ * 2);
    ushort_t* W2H   = (ushort_t*)alloc((long)H_ * 3 * FS_ * 2);
    ushort_t* W2L   = (ushort_t*)alloc((long)H_ * 3 * FS_ * 2);
    ushort_t* pooledH = (ushort_t*)alloc((long)B_ * H_ * 2);
    ushort_t* pooledL = (ushort_t*)alloc((long)B_ * H_ * 2);
    float* Ttab     = (float*)alloc((long)L_ * H_ * 4);
    float* Ptab     = (float*)alloc(6L * H_ * 4);

    // pool aliases (phases disjoint in time):
    //   phase A (qkv+attn+wo): xnH|xnL (ctx reuses) + qb + kb + vb
    //   phase B (convs):       xn2H|xn2L + y1H|y1L (half)
    //   pre-loop: xembH|xembL ; post-loop: embH|embL
    ushort_t* xnH = (ushort_t*)poolC;
    ushort_t* xnL = xnH + ROWE;
    float* qbF = (float*)(poolC + ROWE * 4);
    float* kbF = qbF + ROWE;
    float* vbF = qbF + 2 * ROWE;
    ushort_t* ctxH = xnH;
    ushort_t* ctxL = xnL;
    ushort_t* xn2H = (ushort_t*)poolC;
    ushort_t* xn2L = xn2H + ROWE;
    ushort_t* y1H  = (ushort_t*)(poolC + ROWE * 4);
    ushort_t* y1L  = y1H + (long)MH_ * FS_;
    ushort_t* xembH = (ushort_t*)poolC;
    ushort_t* xembL = xembH + ROWE;
    ushort_t* embH = (ushort_t*)poolC;
    ushort_t* embL = embH + (long)V_ * H_;

    dim3 blk(256);

    // --- init (ws re-poisoned every call) ---
    zero_f32<<<dim3((unsigned)((ROWE + 255) / 256)), blk, 0, stream>>>(prevF, ROWE);
    zero_f32<<<dim3((3 * M_ + 255) / 256), blk, 0, stream>>>(hpF, 3 * M_);
    zero_f32<<<dim3(1), blk, 0, stream>>>((float*)flags, 16);
    zero_f32<<<dim3(1), blk, 0, stream>>>((float*)zpg, 64);
    sig_prep<<<dim3(154), blk, 0, stream>>>(Ttab, Ptab);

    // --- weight prep: transpose + hi/lo split ---
    wsplitT_kernel<<<dim3(1024), blk, 0, stream>>>(proj_w, projH, projL, H_, H_);
    wsplitT_kernel<<<dim3(1024), blk, 0, stream>>>(wq, wqH, wqL, H_, H_);
    wsplitT_kernel<<<dim3(1024), blk, 0, stream>>>(wk, wkH, wkL, H_, H_);
    wsplitT_kernel<<<dim3(1024), blk, 0, stream>>>(wv, wvH, wvL, H_, H_);
    wsplitT_kernel<<<dim3(1024), blk, 0, stream>>>(wo, woH, woL, H_, H_);
    convw_split_kernel<<<dim3(12288), blk, 0, stream>>>(c1_w, W1H, W1L, FS_, H_);
    convw_split_kernel<<<dim3(12288), blk, 0, stream>>>(c2_w, W2H, W2L, H_, FS_);

    // --- embedding + input projection ---
    embed_kernel<<<dim3(M_), blk, 0, stream>>>(story, query, emb, mask_p, xembH, xembL);
    gemm_s<<<dim3(H_ / 128, M_ / 128), blk, 0, stream>>>(
        xembH, xembL, H_, 0, 0, 0, projH, projL, H_, H_,
        nullptr, nullptr, 1.f, 0, 0, 0, trunkF, nullptr, nullptr, nullptr, nullptr, zpg);

    // --- ACT loop: 6 steps with faithful any()-gate ---
    for (int t = 0; t < 6; t++) {
        gate_kernel<<<dim3(M_ / 256), blk, 0, stream>>>(hpF, nuF, flags + t);
        s_pr_kernel<<<dim3(M_ / 4), blk, 0, stream>>>(trunkF, Ttab, Ptab, p_w, p_b,
                                                      hpF, remF, nuF, uwF, flags + t, t);
        ln_kernel<<<dim3(M_ / 4), blk, 0, stream>>>(trunkF, ln1_g, ln1_b, xnH, xnL);
        gemm_s<<<dim3(H_ / 128, M_ / 128), blk, 0, stream>>>(
            xnH, xnL, H_, 0, 0, 0, wqH, wqL, H_, H_,
            nullptr, nullptr, 0.125f, 0, 0, 0, qbF, nullptr, nullptr, nullptr, nullptr, zpg);
        gemm_s<<<dim3(H_ / 128, M_ / 128), blk, 0, stream>>>(
            xnH, xnL, H_, 0, 0, 0, wkH, wkL, H_, H_,
            nullptr, nullptr, 1.f, 0, 0, 0, kbF, nullptr, nullptr, nullptr, nullptr, zpg);
        gemm_s<<<dim3(H_ / 128, M_ / 128), blk, 0, stream>>>(
            xnH, xnL, H_, 0, 0, 0, wvH, wvL, H_, H_,
            nullptr, nullptr, 1.f, 0, 0, 0, vbF, nullptr, nullptr, nullptr, nullptr, zpg);
        attn_kernel<<<dim3(B_ * NH_), blk, 0, stream>>>(qbF, kbF, vbF, ctxH, ctxL);
        gemm_s<<<dim3(H_ / 128, M_ / 128), blk, 0, stream>>>(
            ctxH, ctxL, H_, 0, 0, 0, woH, woL, H_, H_,
            nullptr, trunkF, 1.f, 0, 0, 0, trunkF, nullptr, nullptr, nullptr, nullptr, zpg);
        ln_kernel<<<dim3(M_ / 4), blk, 0, stream>>>(trunkF, ln2_g, ln2_b, xn2H, xn2L);
        for (int half = 0; half < 2; half++) {
            int ro = half * MH_;
            gemm_s<<<dim3(FS_ / 128, MH_ / 128), blk, 0, stream>>>(
                xn2H, xn2L, H_, 1, ro, ro, W1H, W1L, FS_, 3 * H_,
                c1_b, nullptr, 1.f, 1, 0, 2, nullptr, y1H, y1L, nullptr, nullptr, zpg);
            gemm_s<<<dim3(H_ / 128, MH_ / 128), blk, 0, stream>>>(
                y1H, y1L, FS_, 1, 0, ro, W2H, W2L, H_, 3 * FS_,
                c2_b, trunkF, 1.f, 0, ro, 1, trunkF, nullptr, nullptr, prevF, uwF, zpg);
        }
    }

    // --- output head ---
    pooled_kernel<<<dim3(B_ * H_ / 256), blk, 0, stream>>>(prevF, pooledH, pooledL);
    esplit_kernel<<<dim3(64000), blk, 0, stream>>>(emb, embH, embL, (long)V_ * H_);
    gemm_s<<<dim3(V_ / 128, B_ / 128), blk, 0, stream>>>(
        pooledH, pooledL, H_, 0, 0, 0, embH, embL, V_, H_,
        out_b, nullptr, 1.f, 0, 0, 0, outp, nullptr, nullptr, nullptr, nullptr, zpg);
    softmax_kernel<<<dim3(B_), blk, 0, stream>>>(outp, outp + (long)B_ * V_);
    tails_kernel<<<dim3((M_ + 255) / 256), blk, 0, stream>>>(remF, nuF, outp + 2L * B_ * V_);
}